// Round 1
// baseline (2113.286 us; speedup 1.0000x reference)
//
#include <hip/hip_runtime.h>
#include <hip/hip_bf16.h>
#include <math.h>

// ---------------------------------------------------------------------------
// EntityMoELayer: pooling -> MoE(top2 of 8, dense-masked) -> self-attn -> FFN
// Round 1: correctness-first bf16-MFMA pipeline. All GEMMs NT (weights
// pre-transposed to bf16), fp32 accumulate, fp32 softmaxes.
// ---------------------------------------------------------------------------

typedef __bf16 bf16_t;
typedef __bf16 bf16x8 __attribute__((ext_vector_type(8)));
typedef float  f32x4  __attribute__((ext_vector_type(4)));

#define B_   8
#define NE_  1024
#define NO_  8
#define D_   1024
#define E_   8
#define H_   2048
#define O_   1024
#define NH_  8
#define HD_  128
#define FH_  4096
#define T_   8192   // B*NE tokens

// ---------------------------------------------------------------------------
// Generic NT GEMM: C[M,N] = epi( A[M,K] * B[N,K]^T ), bf16 in, fp32 accum.
// 128x128 block tile, 4 waves (2x2 of 64x64), MFMA 16x16x32 bf16, BK=32.
// LDS row stride 40 halves (80B): 16B aligned, uniform bank spread for b128.
// Batch (grid.z): bh = zbase+z, b=bh>>3, h=bh&7; per-operand offset
//   = b*s?b + h*s?h + z*s?z  (covers head-sliced Q/K/ctx and chunked S).
// ---------------------------------------------------------------------------
template<typename OUT_T, bool TRANSC, bool BIAS, bool RELU, bool WSCALE, bool ACCUM>
__global__ __launch_bounds__(256, 2)
void gemm_nt(const bf16_t* __restrict__ A, const bf16_t* __restrict__ Bm,
             OUT_T* __restrict__ C,
             const float* __restrict__ bias, const float* __restrict__ wfull, int expert,
             int K, int lda, int ldb, int ldc, float alpha, int zbase,
             long sAb, long sAh, long sAz,
             long sBb, long sBh, long sBz,
             long sCb, long sCh, long sCz)
{
    const int z  = blockIdx.z;
    const long bh = zbase + z;
    const long bb = bh >> 3, hh = bh & 7;
    A  += bb*sAb + hh*sAh + (long)z*sAz;
    Bm += bb*sBb + hh*sBh + (long)z*sBz;
    C  += bb*sCb + hh*sCh + (long)z*sCz;

    __shared__ __align__(16) bf16_t As[128*40];
    __shared__ __align__(16) bf16_t Bs[128*40];

    const int t    = threadIdx.x;
    const int lane = t & 63, wave = t >> 6;
    const int l16  = lane & 15, quad = lane >> 4;
    const int wm   = (wave & 1) * 64, wn = (wave >> 1) * 64;
    const int rowBase = blockIdx.x * 128;
    const int colBase = blockIdx.y * 128;

    // staging: 128 rows x 32 halves = 512 chunks of 16B per tile; thread does 2
    const int sr = t >> 2;            // row 0..63 (and +64)
    const int sc = (t & 3) * 8;       // halves offset within row (16B chunk)
    const bf16_t* ag0 = A  + (long)(rowBase + sr)*lda + sc;
    const bf16_t* ag1 = ag0 + (long)64*lda;
    const bf16_t* bg0 = Bm + (long)(colBase + sr)*ldb + sc;
    const bf16_t* bg1 = bg0 + (long)64*ldb;
    bf16_t* as0 = &As[sr*40 + sc]; bf16_t* as1 = as0 + 64*40;
    bf16_t* bs0 = &Bs[sr*40 + sc]; bf16_t* bs1 = bs0 + 64*40;

    f32x4 acc[4][4] = {};

    for (int k0 = 0; k0 < K; k0 += 32) {
        uint4 va0 = *(const uint4*)(ag0 + k0);
        uint4 va1 = *(const uint4*)(ag1 + k0);
        uint4 vb0 = *(const uint4*)(bg0 + k0);
        uint4 vb1 = *(const uint4*)(bg1 + k0);
        __syncthreads();
        *(uint4*)as0 = va0; *(uint4*)as1 = va1;
        *(uint4*)bs0 = vb0; *(uint4*)bs1 = vb1;
        __syncthreads();

        bf16x8 af[4], bfr[4];
        #pragma unroll
        for (int mi = 0; mi < 4; mi++)
            af[mi] = *(const bf16x8*)&As[(wm + mi*16 + l16)*40 + quad*8];
        #pragma unroll
        for (int ni = 0; ni < 4; ni++)
            bfr[ni] = *(const bf16x8*)&Bs[(wn + ni*16 + l16)*40 + quad*8];
        #pragma unroll
        for (int mi = 0; mi < 4; mi++)
            #pragma unroll
            for (int ni = 0; ni < 4; ni++)
                acc[mi][ni] = __builtin_amdgcn_mfma_f32_16x16x32_bf16(
                                  af[mi], bfr[ni], acc[mi][ni], 0, 0, 0);
    }

    // epilogue: D[row = quad*4+r][col = l16] per 16x16 tile (m89-verified map)
    #pragma unroll
    for (int mi = 0; mi < 4; mi++) {
        #pragma unroll
        for (int ni = 0; ni < 4; ni++) {
            const int col = colBase + wn + ni*16 + l16;
            float bv = 0.0f;
            if (BIAS) bv = bias[col];
            #pragma unroll
            for (int rr = 0; rr < 4; rr++) {
                const int row = rowBase + wm + mi*16 + quad*4 + rr;
                float v = acc[mi][ni][rr] * alpha;
                if (BIAS)   v += bv;
                if (RELU)   v = fmaxf(v, 0.0f);
                if (WSCALE) v *= wfull[(long)row*8 + expert];
                if (ACCUM) {
                    C[(long)row*ldc + col] += v;          // fp32 accum buffer
                } else if (TRANSC) {
                    C[(long)col*ldc + row] = (OUT_T)v;    // write C^T (for V)
                } else {
                    C[(long)row*ldc + col] = (OUT_T)v;
                }
            }
        }
    }
}

// ---------------------------------------------------------------------------
// fp32 (R x C) -> bf16 transposed (C x R), 64x64 LDS tiles, batched (grid.z)
// ---------------------------------------------------------------------------
__global__ __launch_bounds__(256)
void transpose_convert(const float* __restrict__ in, bf16_t* __restrict__ out,
                       int R, int C, long inStride, long outStride)
{
    __shared__ float tl[64][65];
    const int t = threadIdx.x;
    const float* src = in  + (long)blockIdx.z * inStride;
    bf16_t*      dst = out + (long)blockIdx.z * outStride;
    const int c0 = blockIdx.x * 64, r0 = blockIdx.y * 64;
    #pragma unroll
    for (int i = 0; i < 16; i++) {
        const int idx = t + i*256, r = idx >> 6, c = idx & 63;
        tl[r][c] = src[(long)(r0 + r)*C + c0 + c];
    }
    __syncthreads();
    #pragma unroll
    for (int i = 0; i < 16; i++) {
        const int idx = t + i*256, rT = idx >> 6, cT = idx & 63;
        dst[(long)(c0 + rT)*R + r0 + cT] = (bf16_t)tl[cT][rT];
    }
}

// ---------------------------------------------------------------------------
// Entity pooling: per token (b,n): softmax over NO=8 object logits (x.attn_w),
// weighted sum over objects -> x_agg (fp32 + bf16). One block per token.
// ---------------------------------------------------------------------------
__global__ __launch_bounds__(256)
void pool_kernel(const float* __restrict__ x, const float* __restrict__ attn_w,
                 float* __restrict__ xaggf, bf16_t* __restrict__ xaggb)
{
    __shared__ float xs[8192];      // 8 objects x 1024 dims
    __shared__ float red[32];
    const int t = threadIdx.x;
    const long tok = blockIdx.x;
    const float4* src = (const float4*)(x + tok*8192);
    float4* xs4 = (float4*)xs;
    #pragma unroll
    for (int i = 0; i < 8; i++) xs4[t + i*256] = src[t + i*256];
    float wreg[4];
    #pragma unroll
    for (int j = 0; j < 4; j++) wreg[j] = attn_w[t + j*256];
    __syncthreads();

    float part[8];
    #pragma unroll
    for (int o = 0; o < 8; o++) {
        float p = 0.0f;
        #pragma unroll
        for (int j = 0; j < 4; j++) p += xs[o*1024 + t + j*256] * wreg[j];
        part[o] = p;
    }
    const int lane = t & 63, wv = t >> 6;
    #pragma unroll
    for (int o = 0; o < 8; o++) {
        float v = part[o];
        for (int off = 32; off; off >>= 1) v += __shfl_down(v, off);
        if (lane == 0) red[o*4 + wv] = v;
    }
    __syncthreads();
    float lg[8], mx = -3.4e38f;
    #pragma unroll
    for (int o = 0; o < 8; o++) {
        lg[o] = red[o*4] + red[o*4+1] + red[o*4+2] + red[o*4+3];
        mx = fmaxf(mx, lg[o]);
    }
    float ssum = 0.0f;
    #pragma unroll
    for (int o = 0; o < 8; o++) { lg[o] = expf(lg[o] - mx); ssum += lg[o]; }
    const float inv = 1.0f / ssum;
    #pragma unroll
    for (int j = 0; j < 4; j++) {
        const int d = t + j*256;
        float a = 0.0f;
        #pragma unroll
        for (int o = 0; o < 8; o++) a += lg[o] * xs[o*1024 + d];
        a *= inv;
        xaggf[tok*1024 + d] = a;
        xaggb[tok*1024 + d] = (bf16_t)a;
    }
}

// ---------------------------------------------------------------------------
// Gate: fp32 logits (xagg @ gate_W + b), softmax, top-2 (tie -> lower index,
// matches lax.top_k), renormalized gates scattered into dense wfull[T,8].
// One wave per token.
// ---------------------------------------------------------------------------
__global__ __launch_bounds__(256)
void gate_kernel(const float* __restrict__ xaggf, const float* __restrict__ gate_W,
                 const float* __restrict__ gate_b, float* __restrict__ wfull)
{
    const int t = threadIdx.x;
    const int lane = t & 63, wv = t >> 6;
    const long tok = (long)blockIdx.x*4 + wv;
    const float* xr = xaggf + tok*1024;
    float acc[8] = {0,0,0,0,0,0,0,0};
    for (int j = 0; j < 16; j++) {
        const int d = lane + j*64;
        const float xv = xr[d];
        const float4 w0 = *(const float4*)(gate_W + (long)d*8);
        const float4 w1 = *(const float4*)(gate_W + (long)d*8 + 4);
        acc[0] += xv*w0.x; acc[1] += xv*w0.y; acc[2] += xv*w0.z; acc[3] += xv*w0.w;
        acc[4] += xv*w1.x; acc[5] += xv*w1.y; acc[6] += xv*w1.z; acc[7] += xv*w1.w;
    }
    #pragma unroll
    for (int e = 0; e < 8; e++)
        for (int off = 32; off; off >>= 1) acc[e] += __shfl_down(acc[e], off);
    if (lane == 0) {
        float l[8];
        #pragma unroll
        for (int e = 0; e < 8; e++) l[e] = acc[e] + gate_b[e];
        int i1 = 0; float v1 = l[0];
        #pragma unroll
        for (int e = 1; e < 8; e++) if (l[e] > v1) { v1 = l[e]; i1 = e; }
        int i2 = -1; float v2 = -3.4e38f;
        #pragma unroll
        for (int e = 0; e < 8; e++) if (e != i1 && l[e] > v2) { v2 = l[e]; i2 = e; }
        // renormalized top-2 softmax gates (Z cancels): g1 = 1/(1+e^{l2-l1})
        const float tt = expf(v2 - v1);
        const float g1 = 1.0f/(1.0f + tt), g2 = tt/(1.0f + tt);
        float* wo = wfull + tok*8;
        #pragma unroll
        for (int e = 0; e < 8; e++) wo[e] = 0.0f;
        wo[i1] = g1; wo[i2] = g2;
    }
}

// ---------------------------------------------------------------------------
// Row softmax over 1024 fp32 scores; writes bf16 probs in-place into the
// first half of each row (row stride stays 1024 floats -> P lda = 2048 bf16).
// One block per row. All reads complete before writes (syncthreads between).
// ---------------------------------------------------------------------------
__global__ __launch_bounds__(256)
void softmax_rows(float* __restrict__ S)
{
    __shared__ float redA[4], redB[4];
    const int t = threadIdx.x;
    float* rowp = S + (long)blockIdx.x * 1024;
    const float4 v = ((const float4*)rowp)[t];
    const int lane = t & 63, wv = t >> 6;
    float m = fmaxf(fmaxf(v.x, v.y), fmaxf(v.z, v.w));
    for (int off = 32; off; off >>= 1) m = fmaxf(m, __shfl_down(m, off));
    if (lane == 0) redA[wv] = m;
    __syncthreads();
    m = fmaxf(fmaxf(redA[0], redA[1]), fmaxf(redA[2], redA[3]));
    const float e0 = expf(v.x - m), e1 = expf(v.y - m);
    const float e2 = expf(v.z - m), e3 = expf(v.w - m);
    float s = e0 + e1 + e2 + e3;
    for (int off = 32; off; off >>= 1) s += __shfl_down(s, off);
    if (lane == 0) redB[wv] = s;
    __syncthreads();
    const float inv = 1.0f / (redB[0] + redB[1] + redB[2] + redB[3]);
    union { bf16_t h[4]; uint2 u; } pk;
    pk.h[0] = (bf16_t)(e0*inv); pk.h[1] = (bf16_t)(e1*inv);
    pk.h[2] = (bf16_t)(e2*inv); pk.h[3] = (bf16_t)(e3*inv);
    ((uint2*)rowp)[t] = pk.u;
}

// fp32 -> bf16 elementwise (ent conversion)
__global__ __launch_bounds__(256)
void f2b_kernel(const float* __restrict__ in, bf16_t* __restrict__ out)
{
    const long i = ((long)blockIdx.x*256 + threadIdx.x) * 4;
    const float4 v = *(const float4*)(in + i);
    union { bf16_t h[4]; uint2 u; } pk;
    pk.h[0] = (bf16_t)v.x; pk.h[1] = (bf16_t)v.y;
    pk.h[2] = (bf16_t)v.z; pk.h[3] = (bf16_t)v.w;
    *(uint2*)(out + i) = pk.u;
}

// ---------------------------------------------------------------------------
extern "C" void kernel_launch(void* const* d_in, const int* in_sizes, int n_in,
                              void* d_out, int out_size, void* d_ws, size_t ws_size,
                              hipStream_t stream)
{
    const float* x      = (const float*)d_in[0];
    const float* attn_w = (const float*)d_in[1];
    const float* gate_W = (const float*)d_in[2];
    const float* gate_b = (const float*)d_in[3];
    const float* eW1    = (const float*)d_in[4];
    const float* eb1    = (const float*)d_in[5];
    const float* eW2    = (const float*)d_in[6];
    const float* eb2    = (const float*)d_in[7];
    const float* Wq     = (const float*)d_in[8];   const float* bq = (const float*)d_in[9];
    const float* Wk     = (const float*)d_in[10];  const float* bk = (const float*)d_in[11];
    const float* Wv     = (const float*)d_in[12];  const float* bv = (const float*)d_in[13];
    const float* Wo     = (const float*)d_in[14];  const float* bo = (const float*)d_in[15];
    const float* fW1    = (const float*)d_in[16];  const float* fb1 = (const float*)d_in[17];
    const float* fW2    = (const float*)d_in[18];  const float* fb2 = (const float*)d_in[19];
    float* out = (float*)d_out;

    char* ws = (char*)d_ws;
    size_t off = 0;
    auto alloc = [&](size_t sz) -> void* {
        void* p = (void*)(ws + off);
        off += (sz + 255) & ~(size_t)255;
        return p;
    };
    // bf16 transposed weights (persist whole call)
    bf16_t* WqT  = (bf16_t*)alloc((size_t)O_*O_*2);
    bf16_t* WkT  = (bf16_t*)alloc((size_t)O_*O_*2);
    bf16_t* WvT  = (bf16_t*)alloc((size_t)O_*O_*2);
    bf16_t* WoT  = (bf16_t*)alloc((size_t)O_*O_*2);
    bf16_t* fW1T = (bf16_t*)alloc((size_t)O_*FH_*2);
    bf16_t* fW2T = (bf16_t*)alloc((size_t)FH_*O_*2);
    bf16_t* eW1T = (bf16_t*)alloc((size_t)E_*D_*H_*2);
    bf16_t* eW2T = (bf16_t*)alloc((size_t)E_*H_*O_*2);
    const size_t reuse0 = off;                         // ffn_h aliases from here
    float*  xaggf  = (float*)alloc((size_t)T_*D_*4);
    bf16_t* xaggb  = (bf16_t*)alloc((size_t)T_*D_*2);
    float*  wfull  = (float*)alloc((size_t)T_*E_*4);
    bf16_t* hidden = (bf16_t*)alloc((size_t)T_*H_*2);
    float*  moeacc = (float*)alloc((size_t)T_*O_*4);
    bf16_t* entb   = (bf16_t*)alloc((size_t)T_*O_*2);
    bf16_t* qb     = (bf16_t*)alloc((size_t)T_*O_*2);
    bf16_t* kb     = (bf16_t*)alloc((size_t)T_*O_*2);
    bf16_t* vT     = (bf16_t*)alloc((size_t)O_*T_*2); // V^T: (channel, token)
    float*  S      = (float*)alloc((size_t)16*NE_*NE_*4); // 16-bh score chunk
    bf16_t* ctxb   = (bf16_t*)alloc((size_t)T_*O_*2);
    // aliases (regions dead by the time these are written):
    bf16_t* ffnhb  = (bf16_t*)(ws + reuse0);          // over xaggf..hidden (84MB>67MB)
    bf16_t* relb   = (bf16_t*)moeacc;                 // over moeacc (33MB>16MB)

    const dim3 blk(256);

    // 1) weights -> bf16, transposed (all GEMMs become NT)
    transpose_convert<<<dim3(H_/64, D_/64, E_), blk, 0, stream>>>(eW1, eW1T, D_, H_, (long)D_*H_, (long)D_*H_);
    transpose_convert<<<dim3(O_/64, H_/64, E_), blk, 0, stream>>>(eW2, eW2T, H_, O_, (long)H_*O_, (long)H_*O_);
    transpose_convert<<<dim3(O_/64, O_/64, 1), blk, 0, stream>>>(Wq, WqT, O_, O_, 0, 0);
    transpose_convert<<<dim3(O_/64, O_/64, 1), blk, 0, stream>>>(Wk, WkT, O_, O_, 0, 0);
    transpose_convert<<<dim3(O_/64, O_/64, 1), blk, 0, stream>>>(Wv, WvT, O_, O_, 0, 0);
    transpose_convert<<<dim3(O_/64, O_/64, 1), blk, 0, stream>>>(Wo, WoT, O_, O_, 0, 0);
    transpose_convert<<<dim3(FH_/64, O_/64, 1), blk, 0, stream>>>(fW1, fW1T, O_, FH_, 0, 0);
    transpose_convert<<<dim3(O_/64, FH_/64, 1), blk, 0, stream>>>(fW2, fW2T, FH_, O_, 0, 0);

    // 2) pooling + gating
    pool_kernel<<<dim3(T_), blk, 0, stream>>>(x, attn_w, xaggf, xaggb);
    gate_kernel<<<dim3(T_/4), blk, 0, stream>>>(xaggf, gate_W, gate_b, wfull);

    // 3) MoE (dense over experts; zero-gated experts contribute exactly 0)
    (void)hipMemsetAsync(moeacc, 0, (size_t)T_*O_*4, stream);
    for (int e = 0; e < E_; e++) {
        gemm_nt<bf16_t, false, true, true, false, false><<<dim3(64, 16, 1), blk, 0, stream>>>(
            xaggb, eW1T + (size_t)e*D_*H_, hidden, eb1 + (size_t)e*H_, nullptr, 0,
            D_, D_, D_, H_, 1.0f, 0, 0,0,0, 0,0,0, 0,0,0);
        gemm_nt<float, false, true, false, true, true><<<dim3(64, 8, 1), blk, 0, stream>>>(
            hidden, eW2T + (size_t)e*H_*O_, moeacc, eb2 + (size_t)e*O_, wfull, e,
            H_, H_, H_, O_, 1.0f, 0, 0,0,0, 0,0,0, 0,0,0);
    }
    f2b_kernel<<<dim3(T_*O_/1024), blk, 0, stream>>>(moeacc, entb);

    // 4) QKV projections (V written transposed as (channel, token))
    gemm_nt<bf16_t, false, true, false, false, false><<<dim3(64, 8, 1), blk, 0, stream>>>(
        entb, WqT, qb, bq, nullptr, 0, O_, O_, O_, O_, 1.0f, 0, 0,0,0, 0,0,0, 0,0,0);
    gemm_nt<bf16_t, false, true, false, false, false><<<dim3(64, 8, 1), blk, 0, stream>>>(
        entb, WkT, kb, bk, nullptr, 0, O_, O_, O_, O_, 1.0f, 0, 0,0,0, 0,0,0, 0,0,0);
    gemm_nt<bf16_t, true, true, false, false, false><<<dim3(64, 8, 1), blk, 0, stream>>>(
        entb, WvT, vT, bv, nullptr, 0, O_, O_, O_, T_, 1.0f, 0, 0,0,0, 0,0,0, 0,0,0);

    // 5) attention, 4 chunks of 16 (b,h) slabs
    const float scl = 0.088388347648318447f;  // 1/sqrt(128)
    for (int c = 0; c < 4; c++) {
        const int zb = c * 16;
        // S = scl * Q K^T   (fp32 out)
        gemm_nt<float, false, false, false, false, false><<<dim3(8, 8, 16), blk, 0, stream>>>(
            qb, kb, S, nullptr, nullptr, 0, HD_, O_, O_, NE_, scl, zb,
            (long)NE_*O_, HD_, 0,   (long)NE_*O_, HD_, 0,   0, 0, (long)NE_*NE_);
        softmax_rows<<<dim3(16*NE_), blk, 0, stream>>>(S);
        // ctx = P V   (P bf16 in-place in S rows, lda=2048)
        gemm_nt<bf16_t, false, false, false, false, false><<<dim3(8, 1, 16), blk, 0, stream>>>(
            (const bf16_t*)S, vT, ctxb, nullptr, nullptr, 0, NE_, 2*NE_, T_, O_, 1.0f, zb,
            0, 0, (long)2*NE_*NE_,   (long)NE_, (long)HD_*T_, 0,   (long)NE_*O_, HD_, 0);
    }

    // 6) output projection + FFN
    gemm_nt<bf16_t, false, true, false, false, false><<<dim3(64, 8, 1), blk, 0, stream>>>(
        ctxb, WoT, relb, bo, nullptr, 0, O_, O_, O_, O_, 1.0f, 0, 0,0,0, 0,0,0, 0,0,0);
    gemm_nt<bf16_t, false, true, true, false, false><<<dim3(64, 32, 1), blk, 0, stream>>>(
        relb, fW1T, ffnhb, fb1, nullptr, 0, O_, O_, O_, FH_, 1.0f, 0, 0,0,0, 0,0,0, 0,0,0);
    gemm_nt<float, false, true, false, false, false><<<dim3(64, 8, 1), blk, 0, stream>>>(
        ffnhb, fW2T, out, fb2, nullptr, 0, FH_, FH_, FH_, O_, 1.0f, 0, 0,0,0, 0,0,0, 0,0,0);
}

// Round 2
// 2075.962 us; speedup vs baseline: 1.0180x; 1.0180x over previous
//
#include <hip/hip_runtime.h>
#include <hip/hip_bf16.h>
#include <math.h>

// ---------------------------------------------------------------------------
// EntityMoELayer: pooling -> MoE(top2 of 8, dense-masked) -> self-attn -> FFN
// Round 2: GEMM staging via __builtin_amdgcn_global_load_lds width=16
// (ladder m93->m97: 517->874 TF). LDS tiles unpadded (stride 32 halves) to
// satisfy the wave-uniform-base + lane*16 destination rule (m104/m108).
// ---------------------------------------------------------------------------

typedef __bf16 bf16_t;
typedef __bf16 bf16x8 __attribute__((ext_vector_type(8)));
typedef float  f32x4  __attribute__((ext_vector_type(4)));

#define B_   8
#define NE_  1024
#define NO_  8
#define D_   1024
#define E_   8
#define H_   2048
#define O_   1024
#define NH_  8
#define HD_  128
#define FH_  4096
#define T_   8192   // B*NE tokens

__device__ __forceinline__ void gl2lds16(const bf16_t* g, bf16_t* l) {
    __builtin_amdgcn_global_load_lds(
        (const __attribute__((address_space(1))) unsigned int*)g,
        (__attribute__((address_space(3))) unsigned int*)l,
        16, 0, 0);
}

// ---------------------------------------------------------------------------
// Generic NT GEMM: C[M,N] = epi( A[M,K] * B[N,K]^T ), bf16 in, fp32 accum.
// 128x128 block tile, 4 waves (2x2 of 64x64), MFMA 16x16x32 bf16, BK=32.
// Staging: async global->LDS, 4 issues/thread/K-step (2 A + 2 B), each wave
// issue fills 16 rows (64B/row) at wave-uniform LDS base + lane*16.
// Batch (grid.z): bh = zbase+z, b=bh>>3, h=bh&7; per-operand offset
//   = b*s?b + h*s?h + z*s?z  (covers head-sliced Q/K/ctx and chunked S).
// ---------------------------------------------------------------------------
template<typename OUT_T, bool TRANSC, bool BIAS, bool RELU, bool WSCALE, bool ACCUM>
__global__ __launch_bounds__(256, 2)
void gemm_nt(const bf16_t* __restrict__ A, const bf16_t* __restrict__ Bm,
             OUT_T* __restrict__ C,
             const float* __restrict__ bias, const float* __restrict__ wfull, int expert,
             int K, int lda, int ldb, int ldc, float alpha, int zbase,
             long sAb, long sAh, long sAz,
             long sBb, long sBh, long sBz,
             long sCb, long sCh, long sCz)
{
    const int z  = blockIdx.z;
    const long bh = zbase + z;
    const long bb = bh >> 3, hh = bh & 7;
    A  += bb*sAb + hh*sAh + (long)z*sAz;
    Bm += bb*sBb + hh*sBh + (long)z*sBz;
    C  += bb*sCb + hh*sCh + (long)z*sCz;

    __shared__ __align__(16) bf16_t As[128*32];
    __shared__ __align__(16) bf16_t Bs[128*32];

    const int t    = threadIdx.x;
    const int lane = t & 63, wave = t >> 6;
    const int l16  = lane & 15, quad = lane >> 4;
    const int wm   = (wave & 1) * 64, wn = (wave >> 1) * 64;
    const int rowBase = blockIdx.x * 128;
    const int colBase = blockIdx.y * 128;

    // async staging source: issue j covers rows [j*64 + wave*16, +16);
    // lane -> row += lane/4, 16B chunk = lane%4. LDS dest wave-uniform.
    const int lrow = lane >> 2;
    const int lch  = (lane & 3) * 8;          // halves
    const bf16_t* agp0 = A  + (long)(rowBase + wave*16 + lrow)*lda + lch;
    const bf16_t* agp1 = agp0 + (long)64*lda;
    const bf16_t* bgp0 = Bm + (long)(colBase + wave*16 + lrow)*ldb + lch;
    const bf16_t* bgp1 = bgp0 + (long)64*ldb;
    bf16_t* alp0 = &As[wave*512];             // 512 halves = 16 rows
    bf16_t* alp1 = &As[(4 + wave)*512];
    bf16_t* blp0 = &Bs[wave*512];
    bf16_t* blp1 = &Bs[(4 + wave)*512];

    f32x4 acc[4][4] = {};

    for (int k0 = 0; k0 < K; k0 += 32) {
        __syncthreads();                      // prev iter's ds_reads done
        gl2lds16(agp0 + k0, alp0);
        gl2lds16(agp1 + k0, alp1);
        gl2lds16(bgp0 + k0, blp0);
        gl2lds16(bgp1 + k0, blp1);
        __syncthreads();                      // vmcnt(0) drain + barrier

        bf16x8 af[4], bfr[4];
        #pragma unroll
        for (int mi = 0; mi < 4; mi++)
            af[mi] = *(const bf16x8*)&As[(wm + mi*16 + l16)*32 + quad*8];
        #pragma unroll
        for (int ni = 0; ni < 4; ni++)
            bfr[ni] = *(const bf16x8*)&Bs[(wn + ni*16 + l16)*32 + quad*8];
        #pragma unroll
        for (int mi = 0; mi < 4; mi++)
            #pragma unroll
            for (int ni = 0; ni < 4; ni++)
                acc[mi][ni] = __builtin_amdgcn_mfma_f32_16x16x32_bf16(
                                  af[mi], bfr[ni], acc[mi][ni], 0, 0, 0);
    }

    // epilogue: D[row = quad*4+r][col = l16] per 16x16 tile (m89-verified map)
    #pragma unroll
    for (int mi = 0; mi < 4; mi++) {
        #pragma unroll
        for (int ni = 0; ni < 4; ni++) {
            const int col = colBase + wn + ni*16 + l16;
            float bv = 0.0f;
            if (BIAS) bv = bias[col];
            #pragma unroll
            for (int rr = 0; rr < 4; rr++) {
                const int row = rowBase + wm + mi*16 + quad*4 + rr;
                float v = acc[mi][ni][rr] * alpha;
                if (BIAS)   v += bv;
                if (RELU)   v = fmaxf(v, 0.0f);
                if (WSCALE) v *= wfull[(long)row*8 + expert];
                if (ACCUM) {
                    C[(long)row*ldc + col] += v;          // fp32 accum buffer
                } else if (TRANSC) {
                    C[(long)col*ldc + row] = (OUT_T)v;    // write C^T (for V)
                } else {
                    C[(long)row*ldc + col] = (OUT_T)v;
                }
            }
        }
    }
}

// ---------------------------------------------------------------------------
// fp32 (R x C) -> bf16 transposed (C x R), 64x64 LDS tiles, batched (grid.z)
// ---------------------------------------------------------------------------
__global__ __launch_bounds__(256)
void transpose_convert(const float* __restrict__ in, bf16_t* __restrict__ out,
                       int R, int C, long inStride, long outStride)
{
    __shared__ float tl[64][65];
    const int t = threadIdx.x;
    const float* src = in  + (long)blockIdx.z * inStride;
    bf16_t*      dst = out + (long)blockIdx.z * outStride;
    const int c0 = blockIdx.x * 64, r0 = blockIdx.y * 64;
    #pragma unroll
    for (int i = 0; i < 16; i++) {
        const int idx = t + i*256, r = idx >> 6, c = idx & 63;
        tl[r][c] = src[(long)(r0 + r)*C + c0 + c];
    }
    __syncthreads();
    #pragma unroll
    for (int i = 0; i < 16; i++) {
        const int idx = t + i*256, rT = idx >> 6, cT = idx & 63;
        dst[(long)(c0 + rT)*R + r0 + cT] = (bf16_t)tl[cT][rT];
    }
}

// ---------------------------------------------------------------------------
// Entity pooling: per token (b,n): softmax over NO=8 object logits (x.attn_w),
// weighted sum over objects -> x_agg (fp32 + bf16). One block per token.
// ---------------------------------------------------------------------------
__global__ __launch_bounds__(256)
void pool_kernel(const float* __restrict__ x, const float* __restrict__ attn_w,
                 float* __restrict__ xaggf, bf16_t* __restrict__ xaggb)
{
    __shared__ float xs[8192];      // 8 objects x 1024 dims
    __shared__ float red[32];
    const int t = threadIdx.x;
    const long tok = blockIdx.x;
    const float4* src = (const float4*)(x + tok*8192);
    float4* xs4 = (float4*)xs;
    #pragma unroll
    for (int i = 0; i < 8; i++) xs4[t + i*256] = src[t + i*256];
    float wreg[4];
    #pragma unroll
    for (int j = 0; j < 4; j++) wreg[j] = attn_w[t + j*256];
    __syncthreads();

    float part[8];
    #pragma unroll
    for (int o = 0; o < 8; o++) {
        float p = 0.0f;
        #pragma unroll
        for (int j = 0; j < 4; j++) p += xs[o*1024 + t + j*256] * wreg[j];
        part[o] = p;
    }
    const int lane = t & 63, wv = t >> 6;
    #pragma unroll
    for (int o = 0; o < 8; o++) {
        float v = part[o];
        for (int off = 32; off; off >>= 1) v += __shfl_down(v, off);
        if (lane == 0) red[o*4 + wv] = v;
    }
    __syncthreads();
    float lg[8], mx = -3.4e38f;
    #pragma unroll
    for (int o = 0; o < 8; o++) {
        lg[o] = red[o*4] + red[o*4+1] + red[o*4+2] + red[o*4+3];
        mx = fmaxf(mx, lg[o]);
    }
    float ssum = 0.0f;
    #pragma unroll
    for (int o = 0; o < 8; o++) { lg[o] = expf(lg[o] - mx); ssum += lg[o]; }
    const float inv = 1.0f / ssum;
    #pragma unroll
    for (int j = 0; j < 4; j++) {
        const int d = t + j*256;
        float a = 0.0f;
        #pragma unroll
        for (int o = 0; o < 8; o++) a += lg[o] * xs[o*1024 + d];
        a *= inv;
        xaggf[tok*1024 + d] = a;
        xaggb[tok*1024 + d] = (bf16_t)a;
    }
}

// ---------------------------------------------------------------------------
// Gate: fp32 logits (xagg @ gate_W + b), softmax, top-2 (tie -> lower index,
// matches lax.top_k), renormalized gates scattered into dense wfull[T,8].
// One wave per token.
// ---------------------------------------------------------------------------
__global__ __launch_bounds__(256)
void gate_kernel(const float* __restrict__ xaggf, const float* __restrict__ gate_W,
                 const float* __restrict__ gate_b, float* __restrict__ wfull)
{
    const int t = threadIdx.x;
    const int lane = t & 63, wv = t >> 6;
    const long tok = (long)blockIdx.x*4 + wv;
    const float* xr = xaggf + tok*1024;
    float acc[8] = {0,0,0,0,0,0,0,0};
    for (int j = 0; j < 16; j++) {
        const int d = lane + j*64;
        const float xv = xr[d];
        const float4 w0 = *(const float4*)(gate_W + (long)d*8);
        const float4 w1 = *(const float4*)(gate_W + (long)d*8 + 4);
        acc[0] += xv*w0.x; acc[1] += xv*w0.y; acc[2] += xv*w0.z; acc[3] += xv*w0.w;
        acc[4] += xv*w1.x; acc[5] += xv*w1.y; acc[6] += xv*w1.z; acc[7] += xv*w1.w;
    }
    #pragma unroll
    for (int e = 0; e < 8; e++)
        for (int off = 32; off; off >>= 1) acc[e] += __shfl_down(acc[e], off);
    if (lane == 0) {
        float l[8];
        #pragma unroll
        for (int e = 0; e < 8; e++) l[e] = acc[e] + gate_b[e];
        int i1 = 0; float v1 = l[0];
        #pragma unroll
        for (int e = 1; e < 8; e++) if (l[e] > v1) { v1 = l[e]; i1 = e; }
        int i2 = -1; float v2 = -3.4e38f;
        #pragma unroll
        for (int e = 0; e < 8; e++) if (e != i1 && l[e] > v2) { v2 = l[e]; i2 = e; }
        // renormalized top-2 softmax gates (Z cancels): g1 = 1/(1+e^{l2-l1})
        const float tt = expf(v2 - v1);
        const float g1 = 1.0f/(1.0f + tt), g2 = tt/(1.0f + tt);
        float* wo = wfull + tok*8;
        #pragma unroll
        for (int e = 0; e < 8; e++) wo[e] = 0.0f;
        wo[i1] = g1; wo[i2] = g2;
    }
}

// ---------------------------------------------------------------------------
// Row softmax over 1024 fp32 scores; writes bf16 probs in-place into the
// first half of each row (row stride stays 1024 floats -> P lda = 2048 bf16).
// One block per row.
// ---------------------------------------------------------------------------
__global__ __launch_bounds__(256)
void softmax_rows(float* __restrict__ S)
{
    __shared__ float redA[4], redB[4];
    const int t = threadIdx.x;
    float* rowp = S + (long)blockIdx.x * 1024;
    const float4 v = ((const float4*)rowp)[t];
    const int lane = t & 63, wv = t >> 6;
    float m = fmaxf(fmaxf(v.x, v.y), fmaxf(v.z, v.w));
    for (int off = 32; off; off >>= 1) m = fmaxf(m, __shfl_down(m, off));
    if (lane == 0) redA[wv] = m;
    __syncthreads();
    m = fmaxf(fmaxf(redA[0], redA[1]), fmaxf(redA[2], redA[3]));
    const float e0 = expf(v.x - m), e1 = expf(v.y - m);
    const float e2 = expf(v.z - m), e3 = expf(v.w - m);
    float s = e0 + e1 + e2 + e3;
    for (int off = 32; off; off >>= 1) s += __shfl_down(s, off);
    if (lane == 0) redB[wv] = s;
    __syncthreads();
    const float inv = 1.0f / (redB[0] + redB[1] + redB[2] + redB[3]);
    union { bf16_t h[4]; uint2 u; } pk;
    pk.h[0] = (bf16_t)(e0*inv); pk.h[1] = (bf16_t)(e1*inv);
    pk.h[2] = (bf16_t)(e2*inv); pk.h[3] = (bf16_t)(e3*inv);
    ((uint2*)rowp)[t] = pk.u;
}

// fp32 -> bf16 elementwise (ent conversion)
__global__ __launch_bounds__(256)
void f2b_kernel(const float* __restrict__ in, bf16_t* __restrict__ out)
{
    const long i = ((long)blockIdx.x*256 + threadIdx.x) * 4;
    const float4 v = *(const float4*)(in + i);
    union { bf16_t h[4]; uint2 u; } pk;
    pk.h[0] = (bf16_t)v.x; pk.h[1] = (bf16_t)v.y;
    pk.h[2] = (bf16_t)v.z; pk.h[3] = (bf16_t)v.w;
    *(uint2*)(out + i) = pk.u;
}

// ---------------------------------------------------------------------------
extern "C" void kernel_launch(void* const* d_in, const int* in_sizes, int n_in,
                              void* d_out, int out_size, void* d_ws, size_t ws_size,
                              hipStream_t stream)
{
    const float* x      = (const float*)d_in[0];
    const float* attn_w = (const float*)d_in[1];
    const float* gate_W = (const float*)d_in[2];
    const float* gate_b = (const float*)d_in[3];
    const float* eW1    = (const float*)d_in[4];
    const float* eb1    = (const float*)d_in[5];
    const float* eW2    = (const float*)d_in[6];
    const float* eb2    = (const float*)d_in[7];
    const float* Wq     = (const float*)d_in[8];   const float* bq = (const float*)d_in[9];
    const float* Wk     = (const float*)d_in[10];  const float* bk = (const float*)d_in[11];
    const float* Wv     = (const float*)d_in[12];  const float* bv = (const float*)d_in[13];
    const float* Wo     = (const float*)d_in[14];  const float* bo = (const float*)d_in[15];
    const float* fW1    = (const float*)d_in[16];  const float* fb1 = (const float*)d_in[17];
    const float* fW2    = (const float*)d_in[18];  const float* fb2 = (const float*)d_in[19];
    float* out = (float*)d_out;

    char* ws = (char*)d_ws;
    size_t off = 0;
    auto alloc = [&](size_t sz) -> void* {
        void* p = (void*)(ws + off);
        off += (sz + 255) & ~(size_t)255;
        return p;
    };
    // bf16 transposed weights (persist whole call)
    bf16_t* WqT  = (bf16_t*)alloc((size_t)O_*O_*2);
    bf16_t* WkT  = (bf16_t*)alloc((size_t)O_*O_*2);
    bf16_t* WvT  = (bf16_t*)alloc((size_t)O_*O_*2);
    bf16_t* WoT  = (bf16_t*)alloc((size_t)O_*O_*2);
    bf16_t* fW1T = (bf16_t*)alloc((size_t)O_*FH_*2);
    bf16_t* fW2T = (bf16_t*)alloc((size_t)FH_*O_*2);
    bf16_t* eW1T = (bf16_t*)alloc((size_t)E_*D_*H_*2);
    bf16_t* eW2T = (bf16_t*)alloc((size_t)E_*H_*O_*2);
    const size_t reuse0 = off;                         // ffn_h aliases from here
    float*  xaggf  = (float*)alloc((size_t)T_*D_*4);
    bf16_t* xaggb  = (bf16_t*)alloc((size_t)T_*D_*2);
    float*  wfull  = (float*)alloc((size_t)T_*E_*4);
    bf16_t* hidden = (bf16_t*)alloc((size_t)T_*H_*2);
    float*  moeacc = (float*)alloc((size_t)T_*O_*4);
    bf16_t* entb   = (bf16_t*)alloc((size_t)T_*O_*2);
    bf16_t* qb     = (bf16_t*)alloc((size_t)T_*O_*2);
    bf16_t* kb     = (bf16_t*)alloc((size_t)T_*O_*2);
    bf16_t* vT     = (bf16_t*)alloc((size_t)O_*T_*2); // V^T: (channel, token)
    float*  S      = (float*)alloc((size_t)16*NE_*NE_*4); // 16-bh score chunk
    bf16_t* ctxb   = (bf16_t*)alloc((size_t)T_*O_*2);
    // aliases (regions dead by the time these are written):
    bf16_t* ffnhb  = (bf16_t*)(ws + reuse0);          // over xaggf..hidden (84MB>67MB)
    bf16_t* relb   = (bf16_t*)moeacc;                 // over moeacc (33MB>16MB)

    const dim3 blk(256);

    // 1) weights -> bf16, transposed (all GEMMs become NT)
    transpose_convert<<<dim3(H_/64, D_/64, E_), blk, 0, stream>>>(eW1, eW1T, D_, H_, (long)D_*H_, (long)D_*H_);
    transpose_convert<<<dim3(O_/64, H_/64, E_), blk, 0, stream>>>(eW2, eW2T, H_, O_, (long)H_*O_, (long)H_*O_);
    transpose_convert<<<dim3(O_/64, O_/64, 1), blk, 0, stream>>>(Wq, WqT, O_, O_, 0, 0);
    transpose_convert<<<dim3(O_/64, O_/64, 1), blk, 0, stream>>>(Wk, WkT, O_, O_, 0, 0);
    transpose_convert<<<dim3(O_/64, O_/64, 1), blk, 0, stream>>>(Wv, WvT, O_, O_, 0, 0);
    transpose_convert<<<dim3(O_/64, O_/64, 1), blk, 0, stream>>>(Wo, WoT, O_, O_, 0, 0);
    transpose_convert<<<dim3(FH_/64, O_/64, 1), blk, 0, stream>>>(fW1, fW1T, O_, FH_, 0, 0);
    transpose_convert<<<dim3(O_/64, FH_/64, 1), blk, 0, stream>>>(fW2, fW2T, FH_, O_, 0, 0);

    // 2) pooling + gating
    pool_kernel<<<dim3(T_), blk, 0, stream>>>(x, attn_w, xaggf, xaggb);
    gate_kernel<<<dim3(T_/4), blk, 0, stream>>>(xaggf, gate_W, gate_b, wfull);

    // 3) MoE (dense over experts; zero-gated experts contribute exactly 0)
    (void)hipMemsetAsync(moeacc, 0, (size_t)T_*O_*4, stream);
    for (int e = 0; e < E_; e++) {
        gemm_nt<bf16_t, false, true, true, false, false><<<dim3(64, 16, 1), blk, 0, stream>>>(
            xaggb, eW1T + (size_t)e*D_*H_, hidden, eb1 + (size_t)e*H_, nullptr, 0,
            D_, D_, D_, H_, 1.0f, 0, 0,0,0, 0,0,0, 0,0,0);
        gemm_nt<float, false, true, false, true, true><<<dim3(64, 8, 1), blk, 0, stream>>>(
            hidden, eW2T + (size_t)e*H_*O_, moeacc, eb2 + (size_t)e*O_, wfull, e,
            H_, H_, H_, O_, 1.0f, 0, 0,0,0, 0,0,0, 0,0,0);
    }
    f2b_kernel<<<dim3(T_*O_/1024), blk, 0, stream>>>(moeacc, entb);

    // 4) QKV projections (V written transposed as (channel, token))
    gemm_nt<bf16_t, false, true, false, false, false><<<dim3(64, 8, 1), blk, 0, stream>>>(
        entb, WqT, qb, bq, nullptr, 0, O_, O_, O_, O_, 1.0f, 0, 0,0,0, 0,0,0, 0,0,0);
    gemm_nt<bf16_t, false, true, false, false, false><<<dim3(64, 8, 1), blk, 0, stream>>>(
        entb, WkT, kb, bk, nullptr, 0, O_, O_, O_, O_, 1.0f, 0, 0,0,0, 0,0,0, 0,0,0);
    gemm_nt<bf16_t, true, true, false, false, false><<<dim3(64, 8, 1), blk, 0, stream>>>(
        entb, WvT, vT, bv, nullptr, 0, O_, O_, O_, T_, 1.0f, 0, 0,0,0, 0,0,0, 0,0,0);

    // 5) attention, 4 chunks of 16 (b,h) slabs
    const float scl = 0.088388347648318447f;  // 1/sqrt(128)
    for (int c = 0; c < 4; c++) {
        const int zb = c * 16;
        // S = scl * Q K^T   (fp32 out)
        gemm_nt<float, false, false, false, false, false><<<dim3(8, 8, 16), blk, 0, stream>>>(
            qb, kb, S, nullptr, nullptr, 0, HD_, O_, O_, NE_, scl, zb,
            (long)NE_*O_, HD_, 0,   (long)NE_*O_, HD_, 0,   0, 0, (long)NE_*NE_);
        softmax_rows<<<dim3(16*NE_), blk, 0, stream>>>(S);
        // ctx = P V   (P bf16 in-place in S rows, lda=2048)
        gemm_nt<bf16_t, false, false, false, false, false><<<dim3(8, 1, 16), blk, 0, stream>>>(
            (const bf16_t*)S, vT, ctxb, nullptr, nullptr, 0, NE_, 2*NE_, T_, O_, 1.0f, zb,
            0, 0, (long)2*NE_*NE_,   (long)NE_, (long)HD_*T_, 0,   (long)NE_*O_, HD_, 0);
    }

    // 6) output projection + FFN
    gemm_nt<bf16_t, false, true, false, false, false><<<dim3(64, 8, 1), blk, 0, stream>>>(
        ctxb, WoT, relb, bo, nullptr, 0, O_, O_, O_, O_, 1.0f, 0, 0,0,0, 0,0,0, 0,0,0);
    gemm_nt<bf16_t, false, true, true, false, false><<<dim3(64, 32, 1), blk, 0, stream>>>(
        relb, fW1T, ffnhb, fb1, nullptr, 0, O_, O_, O_, FH_, 1.0f, 0, 0,0,0, 0,0,0, 0,0,0);
    gemm_nt<float, false, true, false, false, false><<<dim3(64, 8, 1), blk, 0, stream>>>(
        ffnhb, fW2T, out, fb2, nullptr, 0, FH_, FH_, FH_, O_, 1.0f, 0, 0,0,0, 0,0,0, 0,0,0);
}